// Round 1
// baseline (345.641 us; speedup 1.0000x reference)
//
#include <hip/hip_runtime.h>

typedef unsigned int u32;
typedef unsigned short u16;
typedef __attribute__((ext_vector_type(4))) float f32x4;
typedef __attribute__((ext_vector_type(8))) short bf16x8;
typedef __attribute__((ext_vector_type(4))) u32 u32x4;

__device__ __forceinline__ u16 f2bf(float f) {
  u32 u = __builtin_bit_cast(u32, f);
  u = u + 0x7FFFu + ((u >> 16) & 1u);
  return (u16)(u >> 16);
}
__device__ __forceinline__ u32 pack2(float a, float b) {
  return (u32)f2bf(a) | ((u32)f2bf(b) << 16);
}

#define MFMA(a, b, c) __builtin_amdgcn_mfma_f32_16x16x32_bf16((a), (b), (c), 0, 0, 0)

// LDS fragment read: row-major buffer, XOR-swizzled within 128B window.
__device__ __forceinline__ bf16x8 lds_frag(const char* buf, int rowBytes, int row, int kByte) {
  return *(const bf16x8*)(buf + row * rowBytes + (kByte ^ ((row & 7) << 4)));
}
// Global fragment read from transposed bf16 weight [out][512], K-contiguous.
__device__ __forceinline__ bf16x8 g_frag(const u16* wt, int row, int k) {
  return *(const bf16x8*)(wt + (size_t)row * 512 + k);
}

// window/token -> flat token index in [B,32,32,32] (C-contiguous per token)
__device__ __forceinline__ int tok_global(int blk, int t) {
  int b = blk >> 9, r = blk & 511;
  int wd = r >> 6, wh = (r >> 3) & 7, ww = r & 7;
  int d = wd * 4 + (t >> 4);
  int h = wh * 4 + ((t >> 2) & 3);
  int w = ww * 4 + (t & 3);
  return ((b * 32 + d) * 32 + h) * 32 + w;
}

// Transpose + bf16-convert weights into workspace: WTq [1536][512], WTp [512][512]
__global__ void prep_weights(const float* __restrict__ wq, const float* __restrict__ wp,
                             u16* __restrict__ wtq, u16* __restrict__ wtp) {
  int idx = blockIdx.x * 512 + threadIdx.x;
  if (idx < 512 * 1536) {
    int i = idx / 1536, o = idx % 1536;     // coalesced read of W_qkv[i][o]
    wtq[o * 512 + i] = f2bf(wq[idx]);
  } else {
    int j = idx - 512 * 1536;
    int i = j >> 9, o = j & 511;
    wtp[o * 512 + i] = f2bf(wp[j]);
  }
}

__global__ __launch_bounds__(512, 2) void fused_win_attn(
    const float* __restrict__ x, const float* __restrict__ bq, const float* __restrict__ bp,
    const u16* __restrict__ wtq, const u16* __restrict__ wtp, float* __restrict__ out) {
  // LDS: [0,16K) x-chunk [64][128] bf16 swizzled; [16K,144K) per-wave bufA(8K)+bufB(8K)
  // After PV, [0,64K) is reused as O [64][512] bf16 swizzled.
  __shared__ char smem[147456];
  char* xc = smem;
  const int tid = threadIdx.x;
  const int wv = tid >> 6;   // wave id == head id
  const int l  = tid & 63;
  const int lr = l & 15;
  const int g  = l >> 4;
  const int blk = blockIdx.x;
  char* bufA = smem + 16384 + wv * 16384;  // Q then P   [64][64] bf16 swz
  char* bufB = bufA + 8192;                // K then V^T [64][64] bf16 swz

  // --- staging precompute: thread loads 16 ch of one token per chunk ---
  const int st = tid >> 3, seg = tid & 7;
  const float* xsrc = x + (size_t)tok_global(blk, st) * 512 + seg * 16;
  const int stw = (st & 7) << 4;
  char* xw0 = xc + st * 256 + ((seg * 32) ^ stw);
  char* xw1 = xc + st * 256 + ((seg * 32 + 16) ^ stw);

  // ================= Phase 1: Q,K = xw @ Wqkv (M=outch, N=t, K=ch) =================
  f32x4 acc[8][4];
#pragma unroll
  for (int i = 0; i < 8; ++i)
#pragma unroll
    for (int j = 0; j < 4; ++j) acc[i][j] = (f32x4)0.f;
  const int qrow0 = wv * 64, krow0 = 512 + wv * 64;

  for (int c = 0; c < 4; ++c) {
    __syncthreads();
    {
      const float4* s4 = (const float4*)(xsrc + c * 128);
      float4 f0 = s4[0], f1 = s4[1], f2 = s4[2], f3 = s4[3];
      u32x4 w0 = {pack2(f0.x, f0.y), pack2(f0.z, f0.w), pack2(f1.x, f1.y), pack2(f1.z, f1.w)};
      u32x4 w1 = {pack2(f2.x, f2.y), pack2(f2.z, f2.w), pack2(f3.x, f3.y), pack2(f3.z, f3.w)};
      *(u32x4*)xw0 = w0;
      *(u32x4*)xw1 = w1;
    }
    __syncthreads();
    for (int kk = 0; kk < 4; ++kk) {
      const int kByte = kk * 64 + g * 16;
      const int kel = c * 128 + kk * 32 + g * 8;
      bf16x8 bx[4];
#pragma unroll
      for (int j = 0; j < 4; ++j) bx[j] = lds_frag(xc, 256, j * 16 + lr, kByte);
#pragma unroll
      for (int i = 0; i < 4; ++i) {
        bf16x8 a = g_frag(wtq, qrow0 + i * 16 + lr, kel);
#pragma unroll
        for (int j = 0; j < 4; ++j) acc[i][j] = MFMA(a, bx[j], acc[i][j]);
      }
#pragma unroll
      for (int i = 0; i < 4; ++i) {
        bf16x8 a = g_frag(wtq, krow0 + i * 16 + lr, kel);
#pragma unroll
        for (int j = 0; j < 4; ++j) acc[4 + i][j] = MFMA(a, bx[j], acc[4 + i][j]);
      }
    }
  }
  // epilogue: +bias, bf16, write Q -> bufA, K -> bufB  (layout [t][d], d-pairs packed)
#pragma unroll
  for (int i = 0; i < 8; ++i) {
    const int dbase = (i & 3) * 16 + g * 4;
    const int och = ((i >= 4) ? 512 : 0) + wv * 64 + dbase;
    float b0 = bq[och], b1 = bq[och + 1], b2 = bq[och + 2], b3 = bq[och + 3];
    char* buf = (i >= 4) ? bufB : bufA;
#pragma unroll
    for (int j = 0; j < 4; ++j) {
      int t = j * 16 + lr;
      f32x4 v = acc[i][j];
      int swz = (t & 7) << 4;
      *(u32*)(buf + t * 128 + ((dbase * 2) ^ swz))     = pack2(v[0] + b0, v[1] + b1);
      *(u32*)(buf + t * 128 + ((dbase * 2 + 4) ^ swz)) = pack2(v[2] + b2, v[3] + b3);
    }
  }
  asm volatile("s_waitcnt lgkmcnt(0)" ::: "memory");

  // ================= Phase 2: S = Q K^T, softmax, write P =================
  f32x4 sf[4][4];
#pragma unroll
  for (int i = 0; i < 4; ++i)
#pragma unroll
    for (int j = 0; j < 4; ++j) sf[i][j] = (f32x4)0.f;
#pragma unroll
  for (int kk = 0; kk < 2; ++kk) {
    const int kByte = kk * 64 + g * 16;
    bf16x8 qa[4], kb[4];
#pragma unroll
    for (int i = 0; i < 4; ++i) qa[i] = lds_frag(bufA, 128, i * 16 + lr, kByte);
#pragma unroll
    for (int j = 0; j < 4; ++j) kb[j] = lds_frag(bufB, 128, j * 16 + lr, kByte);
#pragma unroll
    for (int i = 0; i < 4; ++i)
#pragma unroll
      for (int j = 0; j < 4; ++j) sf[i][j] = MFMA(qa[i], kb[j], sf[i][j]);
  }
  // scale + clip
#pragma unroll
  for (int i = 0; i < 4; ++i)
#pragma unroll
    for (int j = 0; j < 4; ++j)
#pragma unroll
      for (int r = 0; r < 4; ++r) {
        float v = sf[i][j][r] * 0.125f;
        sf[i][j][r] = fminf(fmaxf(v, -10000.f), 10000.f);
      }
  // row softmax: row t = ti*16 + g*4 + r lives across the 16 lanes of group g
#pragma unroll
  for (int ti = 0; ti < 4; ++ti)
#pragma unroll
    for (int r = 0; r < 4; ++r) {
      float m = fmaxf(fmaxf(sf[ti][0][r], sf[ti][1][r]), fmaxf(sf[ti][2][r], sf[ti][3][r]));
      m = fmaxf(m, __shfl_xor(m, 1));
      m = fmaxf(m, __shfl_xor(m, 2));
      m = fmaxf(m, __shfl_xor(m, 4));
      m = fmaxf(m, __shfl_xor(m, 8));
      float sum = 0.f;
#pragma unroll
      for (int sj = 0; sj < 4; ++sj) {
        float p = __expf(sf[ti][sj][r] - m);
        sf[ti][sj][r] = p;
        sum += p;
      }
      sum += __shfl_xor(sum, 1);
      sum += __shfl_xor(sum, 2);
      sum += __shfl_xor(sum, 4);
      sum += __shfl_xor(sum, 8);
      float inv = 1.f / sum;
#pragma unroll
      for (int sj = 0; sj < 4; ++sj) sf[ti][sj][r] *= inv;
    }
  // write P into bufA (Q dead): layout [t][s]
#pragma unroll
  for (int ti = 0; ti < 4; ++ti)
#pragma unroll
    for (int sj = 0; sj < 4; ++sj)
#pragma unroll
      for (int r = 0; r < 4; ++r) {
        int t = ti * 16 + g * 4 + r;
        int s = sj * 16 + lr;
        *(u16*)(bufA + t * 128 + ((s * 2) ^ ((t & 7) << 4))) = f2bf(sf[ti][sj][r]);
      }

  // ================= Phase 3: V = xw @ Wqkv[v cols] (M=t, N=d, K=ch) =================
  f32x4 vac[4][4];
#pragma unroll
  for (int i = 0; i < 4; ++i)
#pragma unroll
    for (int j = 0; j < 4; ++j) vac[i][j] = (f32x4)0.f;
  const int vrow0 = 1024 + wv * 64;
  for (int c = 0; c < 4; ++c) {
    __syncthreads();
    {
      const float4* s4 = (const float4*)(xsrc + c * 128);
      float4 f0 = s4[0], f1 = s4[1], f2 = s4[2], f3 = s4[3];
      u32x4 w0 = {pack2(f0.x, f0.y), pack2(f0.z, f0.w), pack2(f1.x, f1.y), pack2(f1.z, f1.w)};
      u32x4 w1 = {pack2(f2.x, f2.y), pack2(f2.z, f2.w), pack2(f3.x, f3.y), pack2(f3.z, f3.w)};
      *(u32x4*)xw0 = w0;
      *(u32x4*)xw1 = w1;
    }
    __syncthreads();
    for (int kk = 0; kk < 4; ++kk) {
      const int kByte = kk * 64 + g * 16;
      const int kel = c * 128 + kk * 32 + g * 8;
      bf16x8 xa[4];
#pragma unroll
      for (int ti = 0; ti < 4; ++ti) xa[ti] = lds_frag(xc, 256, ti * 16 + lr, kByte);
#pragma unroll
      for (int ni = 0; ni < 4; ++ni) {
        bf16x8 wb = g_frag(wtq, vrow0 + ni * 16 + lr, kel);
#pragma unroll
        for (int ti = 0; ti < 4; ++ti) vac[ti][ni] = MFMA(xa[ti], wb, vac[ti][ni]);
      }
    }
  }
  // write V^T into bufB (K dead): layout [d][s], s-pairs packed
#pragma unroll
  for (int ti = 0; ti < 4; ++ti)
#pragma unroll
    for (int ni = 0; ni < 4; ++ni) {
      int d = ni * 16 + lr;
      float bb = bq[1024 + wv * 64 + d];
      f32x4 v = vac[ti][ni];
      int s0 = ti * 16 + g * 4;
      int swz = (d & 7) << 4;
      *(u32*)(bufB + d * 128 + ((s0 * 2) ^ swz))     = pack2(v[0] + bb, v[1] + bb);
      *(u32*)(bufB + d * 128 + ((s0 * 2 + 4) ^ swz)) = pack2(v[2] + bb, v[3] + bb);
    }
  asm volatile("s_waitcnt lgkmcnt(0)" ::: "memory");

  // ================= Phase 4: O^T = V^T @ P^T (M=d, N=t, K=s) =================
  f32x4 of[4][4];
#pragma unroll
  for (int i = 0; i < 4; ++i)
#pragma unroll
    for (int j = 0; j < 4; ++j) of[i][j] = (f32x4)0.f;
#pragma unroll
  for (int kk = 0; kk < 2; ++kk) {
    const int kByte = kk * 64 + g * 16;
    bf16x8 va[4], pb[4];
#pragma unroll
    for (int di = 0; di < 4; ++di) va[di] = lds_frag(bufB, 128, di * 16 + lr, kByte);
#pragma unroll
    for (int tj = 0; tj < 4; ++tj) pb[tj] = lds_frag(bufA, 128, tj * 16 + lr, kByte);
#pragma unroll
    for (int di = 0; di < 4; ++di)
#pragma unroll
      for (int tj = 0; tj < 4; ++tj) of[di][tj] = MFMA(va[di], pb[tj], of[di][tj]);
  }
  __syncthreads();  // everyone done with x-chunk + all per-wave bufs
  // write O (concat heads) into smem[0..64K): layout [t][512ch] bf16 swizzled
  char* olds = smem;
#pragma unroll
  for (int di = 0; di < 4; ++di)
#pragma unroll
    for (int tj = 0; tj < 4; ++tj) {
      int t = tj * 16 + lr;
      int cb = wv * 128 + di * 32 + g * 8;
      int swz = (t & 7) << 4;
      f32x4 v = of[di][tj];
      *(u32*)(olds + t * 1024 + ((cb) ^ swz))     = pack2(v[0], v[1]);
      *(u32*)(olds + t * 1024 + ((cb + 4) ^ swz)) = pack2(v[2], v[3]);
    }
  __syncthreads();

  // ================= Phase 5: Y = O @ Wproj (M=outch, N=t, K=ch) =================
  f32x4 y[4][4];
#pragma unroll
  for (int i = 0; i < 4; ++i)
#pragma unroll
    for (int j = 0; j < 4; ++j) y[i][j] = (f32x4)0.f;
  for (int kk = 0; kk < 16; ++kk) {
    const int kByte = kk * 64 + g * 16;
    const int kel = kk * 32 + g * 8;
    bf16x8 ob[4];
#pragma unroll
    for (int tj = 0; tj < 4; ++tj) ob[tj] = lds_frag(olds, 1024, tj * 16 + lr, kByte);
#pragma unroll
    for (int mi = 0; mi < 4; ++mi) {
      bf16x8 wa = g_frag(wtp, wv * 64 + mi * 16 + lr, kel);
#pragma unroll
      for (int tj = 0; tj < 4; ++tj) y[mi][tj] = MFMA(wa, ob[tj], y[mi][tj]);
    }
  }
  // epilogue: +bias, coalesced float4 scatter to output
#pragma unroll
  for (int mi = 0; mi < 4; ++mi) {
    const int och = wv * 64 + mi * 16 + g * 4;
    float b0 = bp[och], b1 = bp[och + 1], b2 = bp[och + 2], b3 = bp[och + 3];
#pragma unroll
    for (int tj = 0; tj < 4; ++tj) {
      int t = tj * 16 + lr;
      f32x4 v = y[mi][tj];
      float4 o;
      o.x = v[0] + b0; o.y = v[1] + b1; o.z = v[2] + b2; o.w = v[3] + b3;
      *(float4*)(out + (size_t)tok_global(blk, t) * 512 + och) = o;
    }
  }
}

extern "C" void kernel_launch(void* const* d_in, const int* in_sizes, int n_in,
                              void* d_out, int out_size, void* d_ws, size_t ws_size,
                              hipStream_t stream) {
  const float* x  = (const float*)d_in[0];
  const float* wq = (const float*)d_in[1];
  const float* bq = (const float*)d_in[2];
  const float* wp = (const float*)d_in[3];
  const float* bp = (const float*)d_in[4];
  float* out = (float*)d_out;
  u16* wtq = (u16*)d_ws;            // [1536][512] bf16
  u16* wtp = wtq + 512 * 1536;      // [512][512]  bf16

  prep_weights<<<2048, 512, 0, stream>>>(wq, wp, wtq, wtp);
  fused_win_attn<<<1024, 512, 0, stream>>>(x, bq, bp, wtq, wtp, out);
}